// Round 4
// baseline (1281.390 us; speedup 1.0000x reference)
//
#include <hip/hip_runtime.h>

#define LRELU_ALPHA 0.2f
#define NEG_INF_V  -9.0e15f

// Round-4: split the 149KB-LDS monolith (1 block/CU, VALUBusy 10%, constant
// 2.76 GB "HBM" traffic across 3 different implementations) into small
// high-occupancy kernels with workspace handoff:
//   adj_bits:   adj -> 512x8 u64 bitmask            (ws)
//   gat_phase1: Wh = h@W, wh1 = Wh@a1, wh2 = Wh@a2  (ws, 25.9 MB)
//   gat_phase2: stats + softmax + P@Wh + ELU        (out)
// phase2: 3072 blocks x 256 thr, 28 KB LDS -> 5 blocks/CU (20 waves/CU) for
// real latency hiding; p-tile stored [j][8r] so the FMA loop is 3 LDS instrs
// (3x b128) per 32 FMAs.

#define FMA4(d, s, v)                          \
    d.x = fmaf(s, v.x, d.x);                   \
    d.y = fmaf(s, v.y, d.y);                   \
    d.z = fmaf(s, v.z, d.z);                   \
    d.w = fmaf(s, v.w, d.w);

__global__ __launch_bounds__(512)
void adj_bits_kernel(const float* __restrict__ adj, unsigned long long* __restrict__ bits)
{
    const int tid  = threadIdx.x;
    const int lane = tid & 63;
    const int w    = tid >> 6;
    const int g    = blockIdx.x * 8 + w;   // 0..4095
    const int row  = g >> 3;
    const int k    = g & 7;
    float v = adj[row * 512 + k * 64 + lane];
    unsigned long long m = __ballot(v > 0.f);
    if (lane == 0) bits[row * 8 + k] = m;
}

// ---------------- Phase 1: Wh = h@W, wh1, wh2 (to global ws) ----------------
__global__ __launch_bounds__(512)
void gat_phase1(const float* __restrict__ h, const float* __restrict__ W,
                const float* __restrict__ a,
                float* __restrict__ Whg, float* __restrict__ wh1g,
                float* __restrict__ wh2g)
{
    __shared__ float sU[64 * 68];       // transposed h chunk

    const int tid  = threadIdx.x;
    const int lane = tid & 63;
    const int w    = tid >> 6;
    const int bt   = blockIdx.x;
    const size_t hbase = (size_t)bt * 32768;

    float wreg[64];
    #pragma unroll
    for (int f = 0; f < 64; ++f) wreg[f] = W[f * 64 + lane];
    const float a1v = a[lane];
    const float a2v = a[64 + lane];

    for (int c = 0; c < 8; ++c) {
        __syncthreads();
        #pragma unroll
        for (int k = 0; k < 8; ++k) {
            int e = k * 512 + tid;
            sU[(e & 63) * 68 + (e >> 6)] = h[hbase + (size_t)c * 4096 + e];
        }
        __syncthreads();

        float acc[8];
        #pragma unroll
        for (int r = 0; r < 8; ++r) acc[r] = 0.f;
        #pragma unroll
        for (int f = 0; f < 64; ++f) {
            float4 hA = *(const float4*)&sU[f * 68 + w * 8];
            float4 hB = *(const float4*)&sU[f * 68 + w * 8 + 4];
            float wv = wreg[f];
            acc[0] = fmaf(hA.x, wv, acc[0]);
            acc[1] = fmaf(hA.y, wv, acc[1]);
            acc[2] = fmaf(hA.z, wv, acc[2]);
            acc[3] = fmaf(hA.w, wv, acc[3]);
            acc[4] = fmaf(hB.x, wv, acc[4]);
            acc[5] = fmaf(hB.y, wv, acc[5]);
            acc[6] = fmaf(hB.z, wv, acc[6]);
            acc[7] = fmaf(hB.w, wv, acc[7]);
        }
        #pragma unroll
        for (int r = 0; r < 8; ++r) {
            int n = c * 64 + w * 8 + r;
            Whg[hbase + (size_t)n * 64 + lane] = acc[r];
            float t1 = acc[r] * a1v;
            float t2 = acc[r] * a2v;
            #pragma unroll
            for (int s = 32; s > 0; s >>= 1) {
                t1 += __shfl_xor(t1, s);
                t2 += __shfl_xor(t2, s);
            }
            if (lane == 0) { wh1g[bt * 512 + n] = t1; wh2g[bt * 512 + n] = t2; }
        }
    }
}

// ---------------- Phase 2: stats + softmax + P@Wh + ELU ----------------
// block = 256 thr (4 waves); handles rows i0..i0+31 of one bt.
// wave wv owns rows i0+wv*8 .. +7 end-to-end (stats, p, accumulate).
__global__ __launch_bounds__(256)
void gat_phase2(const float* __restrict__ Whg, const float* __restrict__ wh1g,
                const float* __restrict__ wh2g,
                const unsigned long long* __restrict__ bits,
                float* __restrict__ out)
{
    __shared__ float swh2[512];
    __shared__ float swh1[32];
    __shared__ float whc[64 * 68];      // Wh chunk [64 j][64 o + pad]
    __shared__ float ptile[4 * 512];    // per-wave p [64 j][8 r]

    const int tid  = threadIdx.x;
    const int lane = tid & 63;
    const int wv   = tid >> 6;
    const int bx   = blockIdx.x;
    const int bt   = bx >> 4;
    const int i0   = (bx & 15) * 32;
    const size_t whbase = (size_t)bt * 32768;
    const unsigned long long lmask = 1ull << lane;

    swh2[tid]       = wh2g[bt * 512 + tid];
    swh2[tid + 256] = wh2g[bt * 512 + tid + 256];
    if (tid < 32) swh1[tid] = wh1g[bt * 512 + i0 + tid];
    __syncthreads();

    // ---- stats for this wave's 8 rows (lanes over j)
    float wh1r[8], mr[8], invr[8];
    #pragma unroll
    for (int r = 0; r < 8; ++r) {
        const int row = i0 + wv * 8 + r;
        const float wh1v = swh1[wv * 8 + r];
        wh1r[r] = wh1v;
        const unsigned long long* mrow = bits + (size_t)row * 8;
        float att[8];
        float mx = NEG_INF_V;
        #pragma unroll
        for (int k = 0; k < 8; ++k) {
            float e = wh1v + swh2[k * 64 + lane];
            e = (e > 0.f) ? e : LRELU_ALPHA * e;
            att[k] = (mrow[k] & lmask) ? e : NEG_INF_V;
            mx = fmaxf(mx, att[k]);
        }
        #pragma unroll
        for (int s = 32; s > 0; s >>= 1) mx = fmaxf(mx, __shfl_xor(mx, s));
        float sum = 0.f;
        #pragma unroll
        for (int k = 0; k < 8; ++k) sum += __expf(att[k] - mx);
        #pragma unroll
        for (int s = 32; s > 0; s >>= 1) sum += __shfl_xor(sum, s);
        mr[r] = mx;
        invr[r] = 1.f / sum;
    }

    float4 oacc[8];
    #pragma unroll
    for (int r = 0; r < 8; ++r) oacc[r] = make_float4(0.f, 0.f, 0.f, 0.f);

    float* pw = &ptile[wv * 512];
    const int o4 = (lane & 15) * 4;
    const int jq = lane >> 4;

    #pragma unroll 1
    for (int cc = 0; cc < 8; ++cc) {
        __syncthreads();                 // protect whc from previous FMA reads
        // ---- stage Wh chunk (coalesced float4)
        #pragma unroll
        for (int k = 0; k < 4; ++k) {
            int idx = k * 256 + tid;     // 0..1023 float4s
            int j   = idx >> 4;
            int o   = (idx & 15) * 4;
            *(float4*)&whc[j * 68 + o] =
                *(const float4*)&Whg[whbase + (size_t)cc * 4096 + idx * 4];
        }
        __syncthreads();

        // ---- p for this wave's rows (lane = local j), straight to ptile
        float wh2j = swh2[cc * 64 + lane];
        float pv[8];
        #pragma unroll
        for (int r = 0; r < 8; ++r) {
            const int row = i0 + wv * 8 + r;
            float e = wh1r[r] + wh2j;
            e = (e > 0.f) ? e : LRELU_ALPHA * e;
            float av = (bits[(size_t)row * 8 + cc] & lmask) ? e : NEG_INF_V;
            pv[r] = __expf(av - mr[r]) * invr[r];
        }
        *(float4*)&pw[lane * 8]     = make_float4(pv[0], pv[1], pv[2], pv[3]);
        *(float4*)&pw[lane * 8 + 4] = make_float4(pv[4], pv[5], pv[6], pv[7]);
        // same-wave DS ops are in-order: no barrier needed for ptile.

        // ---- FMA: lane=(o4,jq); 3 b128 LDS reads per 32 FMAs
        #pragma unroll 2
        for (int l = 0; l < 16; ++l) {
            int jl = l * 4 + jq;
            float4 whv = *(const float4*)&whc[jl * 68 + o4];
            float4 pa  = *(const float4*)&pw[jl * 8];
            float4 pb  = *(const float4*)&pw[jl * 8 + 4];
            FMA4(oacc[0], pa.x, whv);
            FMA4(oacc[1], pa.y, whv);
            FMA4(oacc[2], pa.z, whv);
            FMA4(oacc[3], pa.w, whv);
            FMA4(oacc[4], pb.x, whv);
            FMA4(oacc[5], pb.y, whv);
            FMA4(oacc[6], pb.z, whv);
            FMA4(oacc[7], pb.w, whv);
        }
    }

    // ---- reduce over jq groups, ELU, store
    const size_t obase = (size_t)bt * 32768;
    #pragma unroll
    for (int r = 0; r < 8; ++r) {
        float4 v = oacc[r];
        #pragma unroll
        for (int s = 16; s <= 32; s <<= 1) {
            v.x += __shfl_xor(v.x, s);
            v.y += __shfl_xor(v.y, s);
            v.z += __shfl_xor(v.z, s);
            v.w += __shfl_xor(v.w, s);
        }
        if (jq == 0) {
            float4 res;
            res.x = (v.x > 0.f) ? v.x : __expf(v.x) - 1.f;
            res.y = (v.y > 0.f) ? v.y : __expf(v.y) - 1.f;
            res.z = (v.z > 0.f) ? v.z : __expf(v.z) - 1.f;
            res.w = (v.w > 0.f) ? v.w : __expf(v.w) - 1.f;
            *(float4*)&out[obase + (size_t)(i0 + wv * 8 + r) * 64 + o4] = res;
        }
    }
}

extern "C" void kernel_launch(void* const* d_in, const int* in_sizes, int n_in,
                              void* d_out, int out_size, void* d_ws, size_t ws_size,
                              hipStream_t stream)
{
    const float* h   = (const float*)d_in[0];   // (16,12,512,64)
    const float* adj = (const float*)d_in[1];   // (512,512)
    const float* W   = (const float*)d_in[2];   // (64,64)
    const float* a   = (const float*)d_in[3];   // (128,1)
    float* out = (float*)d_out;                 // (16,12,512,64)

    // workspace layout (needs ~26 MB)
    unsigned long long* bits = (unsigned long long*)d_ws;            // 32 KB
    float* Whg  = (float*)((char*)d_ws + 32768);                     // 25.17 MB
    float* wh1g = Whg + (size_t)192 * 512 * 64;                      // 384 KB
    float* wh2g = wh1g + (size_t)192 * 512;                          // 384 KB

    adj_bits_kernel<<<512, 512, 0, stream>>>(adj, bits);
    gat_phase1<<<192, 512, 0, stream>>>(h, W, a, Whg, wh1g, wh2g);
    gat_phase2<<<3072, 256, 0, stream>>>(Whg, wh1g, wh2g, bits, out);
}

// Round 6
// 1192.996 us; speedup vs baseline: 1.0741x; 1.0741x over previous
//
#include <hip/hip_runtime.h>

#define LRELU_ALPHA 0.2f
#define NEG_INF_V  -9.0e15f

// Round-6: round-5's phase-1 restructure (256thr/32-chunk/stride-36) broke
// correctness (absmax 8.1e-2) in a way inspection couldn't locate -> revert to
// round-4's twice-proven phase-1 VERBATIM with exactly ONE change:
// `#pragma unroll 1` on the chunk loop. Theory: round-4's 1.75GB/0.92GB
// traffic = LLVM fully unrolling the 8-chunk outer loop around the unrolled
// 64xFMA4 body (4096-FMA straight line, live-set >> 128-VGPR cap at 512thr)
// -> scratch spill. The f-loop MUST stay fully unrolled (partial unroll makes
// wreg[f] dynamically indexed -> scratch, the round-1 lesson).
// adj_bits + phase2 byte-identical to rounds 4/5.

#define FMA4(d, s, v)                          \
    d.x = fmaf(s, v.x, d.x);                   \
    d.y = fmaf(s, v.y, d.y);                   \
    d.z = fmaf(s, v.z, d.z);                   \
    d.w = fmaf(s, v.w, d.w);

__global__ __launch_bounds__(512)
void adj_bits_kernel(const float* __restrict__ adj, unsigned long long* __restrict__ bits)
{
    const int tid  = threadIdx.x;
    const int lane = tid & 63;
    const int w    = tid >> 6;
    const int g    = blockIdx.x * 8 + w;   // 0..4095
    const int row  = g >> 3;
    const int k    = g & 7;
    float v = adj[row * 512 + k * 64 + lane];
    unsigned long long m = __ballot(v > 0.f);
    if (lane == 0) bits[row * 8 + k] = m;
}

// ---------------- Phase 1: Wh = h@W, wh1, wh2 (to global ws) ----------------
// Round-4 phase1 verbatim + `#pragma unroll 1` on the c-loop (the only delta).
__global__ __launch_bounds__(512)
void gat_phase1(const float* __restrict__ h, const float* __restrict__ W,
                const float* __restrict__ a,
                float* __restrict__ Whg, float* __restrict__ wh1g,
                float* __restrict__ wh2g)
{
    __shared__ float sU[64 * 68];       // transposed h chunk

    const int tid  = threadIdx.x;
    const int lane = tid & 63;
    const int w    = tid >> 6;
    const int bt   = blockIdx.x;
    const size_t hbase = (size_t)bt * 32768;

    float wreg[64];
    #pragma unroll
    for (int f = 0; f < 64; ++f) wreg[f] = W[f * 64 + lane];
    const float a1v = a[lane];
    const float a2v = a[64 + lane];

    #pragma unroll 1                    // THE fix: outer full-unroll caused the spill
    for (int c = 0; c < 8; ++c) {
        __syncthreads();
        #pragma unroll
        for (int k = 0; k < 8; ++k) {
            int e = k * 512 + tid;
            sU[(e & 63) * 68 + (e >> 6)] = h[hbase + (size_t)c * 4096 + e];
        }
        __syncthreads();

        float acc[8];
        #pragma unroll
        for (int r = 0; r < 8; ++r) acc[r] = 0.f;
        #pragma unroll
        for (int f = 0; f < 64; ++f) {
            float4 hA = *(const float4*)&sU[f * 68 + w * 8];
            float4 hB = *(const float4*)&sU[f * 68 + w * 8 + 4];
            float wv = wreg[f];
            acc[0] = fmaf(hA.x, wv, acc[0]);
            acc[1] = fmaf(hA.y, wv, acc[1]);
            acc[2] = fmaf(hA.z, wv, acc[2]);
            acc[3] = fmaf(hA.w, wv, acc[3]);
            acc[4] = fmaf(hB.x, wv, acc[4]);
            acc[5] = fmaf(hB.y, wv, acc[5]);
            acc[6] = fmaf(hB.z, wv, acc[6]);
            acc[7] = fmaf(hB.w, wv, acc[7]);
        }
        #pragma unroll
        for (int r = 0; r < 8; ++r) {
            int n = c * 64 + w * 8 + r;
            Whg[hbase + (size_t)n * 64 + lane] = acc[r];
            float t1 = acc[r] * a1v;
            float t2 = acc[r] * a2v;
            #pragma unroll
            for (int s = 32; s > 0; s >>= 1) {
                t1 += __shfl_xor(t1, s);
                t2 += __shfl_xor(t2, s);
            }
            if (lane == 0) { wh1g[bt * 512 + n] = t1; wh2g[bt * 512 + n] = t2; }
        }
    }
}

// ---------------- Phase 2: stats + softmax + P@Wh + ELU ----------------
// (byte-identical to rounds 4/5)
__global__ __launch_bounds__(256)
void gat_phase2(const float* __restrict__ Whg, const float* __restrict__ wh1g,
                const float* __restrict__ wh2g,
                const unsigned long long* __restrict__ bits,
                float* __restrict__ out)
{
    __shared__ float swh2[512];
    __shared__ float swh1[32];
    __shared__ float whc[64 * 68];      // Wh chunk [64 j][64 o + pad]
    __shared__ float ptile[4 * 512];    // per-wave p [64 j][8 r]

    const int tid  = threadIdx.x;
    const int lane = tid & 63;
    const int wv   = tid >> 6;
    const int bx   = blockIdx.x;
    const int bt   = bx >> 4;
    const int i0   = (bx & 15) * 32;
    const size_t whbase = (size_t)bt * 32768;
    const unsigned long long lmask = 1ull << lane;

    swh2[tid]       = wh2g[bt * 512 + tid];
    swh2[tid + 256] = wh2g[bt * 512 + tid + 256];
    if (tid < 32) swh1[tid] = wh1g[bt * 512 + i0 + tid];
    __syncthreads();

    // ---- stats for this wave's 8 rows (lanes over j)
    float wh1r[8], mr[8], invr[8];
    #pragma unroll
    for (int r = 0; r < 8; ++r) {
        const int row = i0 + wv * 8 + r;
        const float wh1v = swh1[wv * 8 + r];
        wh1r[r] = wh1v;
        const unsigned long long* mrow = bits + (size_t)row * 8;
        float att[8];
        float mx = NEG_INF_V;
        #pragma unroll
        for (int k = 0; k < 8; ++k) {
            float e = wh1v + swh2[k * 64 + lane];
            e = (e > 0.f) ? e : LRELU_ALPHA * e;
            att[k] = (mrow[k] & lmask) ? e : NEG_INF_V;
            mx = fmaxf(mx, att[k]);
        }
        #pragma unroll
        for (int s = 32; s > 0; s >>= 1) mx = fmaxf(mx, __shfl_xor(mx, s));
        float sum = 0.f;
        #pragma unroll
        for (int k = 0; k < 8; ++k) sum += __expf(att[k] - mx);
        #pragma unroll
        for (int s = 32; s > 0; s >>= 1) sum += __shfl_xor(sum, s);
        mr[r] = mx;
        invr[r] = 1.f / sum;
    }

    float4 oacc[8];
    #pragma unroll
    for (int r = 0; r < 8; ++r) oacc[r] = make_float4(0.f, 0.f, 0.f, 0.f);

    float* pw = &ptile[wv * 512];
    const int o4 = (lane & 15) * 4;
    const int jq = lane >> 4;

    #pragma unroll 1
    for (int cc = 0; cc < 8; ++cc) {
        __syncthreads();                 // protect whc from previous FMA reads
        // ---- stage Wh chunk (coalesced float4)
        #pragma unroll
        for (int k = 0; k < 4; ++k) {
            int idx = k * 256 + tid;     // 0..1023 float4s
            int j   = idx >> 4;
            int o   = (idx & 15) * 4;
            *(float4*)&whc[j * 68 + o] =
                *(const float4*)&Whg[whbase + (size_t)cc * 4096 + idx * 4];
        }
        __syncthreads();

        // ---- p for this wave's rows (lane = local j), straight to ptile
        float wh2j = swh2[cc * 64 + lane];
        float pv[8];
        #pragma unroll
        for (int r = 0; r < 8; ++r) {
            const int row = i0 + wv * 8 + r;
            float e = wh1r[r] + wh2j;
            e = (e > 0.f) ? e : LRELU_ALPHA * e;
            float av = (bits[(size_t)row * 8 + cc] & lmask) ? e : NEG_INF_V;
            pv[r] = __expf(av - mr[r]) * invr[r];
        }
        *(float4*)&pw[lane * 8]     = make_float4(pv[0], pv[1], pv[2], pv[3]);
        *(float4*)&pw[lane * 8 + 4] = make_float4(pv[4], pv[5], pv[6], pv[7]);
        // same-wave DS ops are in-order: no barrier needed for ptile.

        // ---- FMA: lane=(o4,jq); 3 b128 LDS reads per 32 FMAs
        #pragma unroll 2
        for (int l = 0; l < 16; ++l) {
            int jl = l * 4 + jq;
            float4 whv = *(const float4*)&whc[jl * 68 + o4];
            float4 pa  = *(const float4*)&pw[jl * 8];
            float4 pb  = *(const float4*)&pw[jl * 8 + 4];
            FMA4(oacc[0], pa.x, whv);
            FMA4(oacc[1], pa.y, whv);
            FMA4(oacc[2], pa.z, whv);
            FMA4(oacc[3], pa.w, whv);
            FMA4(oacc[4], pb.x, whv);
            FMA4(oacc[5], pb.y, whv);
            FMA4(oacc[6], pb.z, whv);
            FMA4(oacc[7], pb.w, whv);
        }
    }

    // ---- reduce over jq groups, ELU, store
    const size_t obase = (size_t)bt * 32768;
    #pragma unroll
    for (int r = 0; r < 8; ++r) {
        float4 v = oacc[r];
        #pragma unroll
        for (int s = 16; s <= 32; s <<= 1) {
            v.x += __shfl_xor(v.x, s);
            v.y += __shfl_xor(v.y, s);
            v.z += __shfl_xor(v.z, s);
            v.w += __shfl_xor(v.w, s);
        }
        if (jq == 0) {
            float4 res;
            res.x = (v.x > 0.f) ? v.x : __expf(v.x) - 1.f;
            res.y = (v.y > 0.f) ? v.y : __expf(v.y) - 1.f;
            res.z = (v.z > 0.f) ? v.z : __expf(v.z) - 1.f;
            res.w = (v.w > 0.f) ? v.w : __expf(v.w) - 1.f;
            *(float4*)&out[obase + (size_t)(i0 + wv * 8 + r) * 64 + o4] = res;
        }
    }
}

extern "C" void kernel_launch(void* const* d_in, const int* in_sizes, int n_in,
                              void* d_out, int out_size, void* d_ws, size_t ws_size,
                              hipStream_t stream)
{
    const float* h   = (const float*)d_in[0];   // (16,12,512,64)
    const float* adj = (const float*)d_in[1];   // (512,512)
    const float* W   = (const float*)d_in[2];   // (64,64)
    const float* a   = (const float*)d_in[3];   // (128,1)
    float* out = (float*)d_out;                 // (16,12,512,64)

    // workspace layout (needs ~26 MB)
    unsigned long long* bits = (unsigned long long*)d_ws;            // 32 KB
    float* Whg  = (float*)((char*)d_ws + 32768);                     // 25.17 MB
    float* wh1g = Whg + (size_t)192 * 512 * 64;                      // 384 KB
    float* wh2g = wh1g + (size_t)192 * 512;                          // 384 KB

    adj_bits_kernel<<<512, 512, 0, stream>>>(adj, bits);
    gat_phase1<<<192, 512, 0, stream>>>(h, W, a, Whg, wh1g, wh2g);
    gat_phase2<<<3072, 256, 0, stream>>>(Whg, wh1g, wh2g, bits, out);
}

// Round 7
// 266.059 us; speedup vs baseline: 4.8162x; 4.4839x over previous
//
#include <hip/hip_runtime.h>

#define LRELU_ALPHA 0.2f
#define NEG_INF_V  -9.0e15f

// Round-7: five phase-1 variants sharing the wreg[64] + wave-uniform-float4-
// LDS-read skeleton all produced identical 1.75GB/0.92GB phantom traffic
// (unroll pragmas, block size, chunk size all no-ops). Phase-2's idiom
// (lane-varying b128 LDS reads, small reg arrays) measured ~0 excess bytes.
// => phase1 rewritten as a mirror of phase2's FMA structure:
//   per 64-node chunk: hT[k][n] + sW[k][o] in LDS; lane=(o4,jq); acc[16]x f4;
//   jq covers k%4 classes; shfl-reduce over jq; fused wh1/wh2 dot + store.
// adj_bits + phase2 byte-identical to round 6.

#define FMA4(d, s, v)                          \
    d.x = fmaf(s, v.x, d.x);                   \
    d.y = fmaf(s, v.y, d.y);                   \
    d.z = fmaf(s, v.z, d.z);                   \
    d.w = fmaf(s, v.w, d.w);

__global__ __launch_bounds__(512)
void adj_bits_kernel(const float* __restrict__ adj, unsigned long long* __restrict__ bits)
{
    const int tid  = threadIdx.x;
    const int lane = tid & 63;
    const int w    = tid >> 6;
    const int g    = blockIdx.x * 8 + w;   // 0..4095
    const int row  = g >> 3;
    const int k    = g & 7;
    float v = adj[row * 512 + k * 64 + lane];
    unsigned long long m = __ballot(v > 0.f);
    if (lane == 0) bits[row * 8 + k] = m;
}

// ---------------- Phase 1: Wh = h@W, wh1, wh2 (to global ws) ----------------
// 192 blocks x 256 thr. Per 64-node chunk: Wh[n][o] = sum_k h[n][k] W[k][o].
// lane = (o4 = (lane&15)*4, jq = lane>>4); thread accumulates k = jq (mod 4);
// wave wv owns nodes wv*16..+15 of the chunk.
__global__ __launch_bounds__(256)
void gat_phase1(const float* __restrict__ h, const float* __restrict__ W,
                const float* __restrict__ a,
                float* __restrict__ Whg, float* __restrict__ wh1g,
                float* __restrict__ wh2g)
{
    __shared__ float sW[64 * 68];     // [k][o + pad]
    __shared__ float hT[64 * 68];     // [k][n_local + pad]

    const int tid  = threadIdx.x;
    const int lane = tid & 63;
    const int wv   = tid >> 6;        // 0..3
    const int bt   = blockIdx.x;
    const size_t base = (size_t)bt * 32768;

    const int o4 = (lane & 15) * 4;
    const int jq = lane >> 4;

    // stage W [k][o]: idx = k*64+o; lane-consecutive reads
    #pragma unroll
    for (int t = 0; t < 16; ++t) {
        int idx = t * 256 + tid;
        sW[(idx >> 6) * 68 + (idx & 63)] = W[idx];
    }
    const float4 a1v = *(const float4*)&a[o4];
    const float4 a2v = *(const float4*)&a[64 + o4];

    #pragma unroll 1
    for (int c = 0; c < 8; ++c) {
        const int n0 = c * 64;
        __syncthreads();              // prev chunk's readers done (also covers sW staging)
        // stage hT[k][n_local] from h[n0+n][k]; elem idx = t*256+tid:
        // n_local = t*4+wv, k = lane (coalesced 256B reads)
        #pragma unroll
        for (int t = 0; t < 16; ++t) {
            hT[lane * 68 + t * 4 + wv] = h[base + (size_t)(n0 + t * 4 + wv) * 64 + lane];
        }
        __syncthreads();

        float4 acc[16];
        #pragma unroll
        for (int r = 0; r < 16; ++r) acc[r] = make_float4(0.f, 0.f, 0.f, 0.f);

        #pragma unroll 4
        for (int l = 0; l < 16; ++l) {
            int k = l * 4 + jq;
            float4 w4 = *(const float4*)&sW[k * 68 + o4];          // lane-varying
            const float* hrow = &hT[k * 68 + wv * 16];
            float4 ha = *(const float4*)&hrow[0];
            float4 hb = *(const float4*)&hrow[4];
            float4 hc = *(const float4*)&hrow[8];
            float4 hd = *(const float4*)&hrow[12];
            FMA4(acc[0],  ha.x, w4);
            FMA4(acc[1],  ha.y, w4);
            FMA4(acc[2],  ha.z, w4);
            FMA4(acc[3],  ha.w, w4);
            FMA4(acc[4],  hb.x, w4);
            FMA4(acc[5],  hb.y, w4);
            FMA4(acc[6],  hb.z, w4);
            FMA4(acc[7],  hb.w, w4);
            FMA4(acc[8],  hc.x, w4);
            FMA4(acc[9],  hc.y, w4);
            FMA4(acc[10], hc.z, w4);
            FMA4(acc[11], hc.w, w4);
            FMA4(acc[12], hd.x, w4);
            FMA4(acc[13], hd.y, w4);
            FMA4(acc[14], hd.z, w4);
            FMA4(acc[15], hd.w, w4);
        }

        // reduce over jq (lane bits 4,5); jq==0 lanes (0..15) hold Wh[n][o4..o4+3]
        #pragma unroll
        for (int r = 0; r < 16; ++r) {
            float4 v = acc[r];
            #pragma unroll
            for (int s = 16; s <= 32; s <<= 1) {
                v.x += __shfl_xor(v.x, s);
                v.y += __shfl_xor(v.y, s);
                v.z += __shfl_xor(v.z, s);
                v.w += __shfl_xor(v.w, s);
            }
            if (jq == 0) {
                const int n = n0 + wv * 16 + r;
                *(float4*)&Whg[base + (size_t)n * 64 + o4] = v;
                float t1 = v.x * a1v.x + v.y * a1v.y + v.z * a1v.z + v.w * a1v.w;
                float t2 = v.x * a2v.x + v.y * a2v.y + v.z * a2v.z + v.w * a2v.w;
                #pragma unroll
                for (int s = 1; s <= 8; s <<= 1) {   // lanes 0..15 all active
                    t1 += __shfl_xor(t1, s);
                    t2 += __shfl_xor(t2, s);
                }
                if (lane == 0) { wh1g[bt * 512 + n] = t1; wh2g[bt * 512 + n] = t2; }
            }
        }
    }
}

// ---------------- Phase 2: stats + softmax + P@Wh + ELU ----------------
// (byte-identical to rounds 4/5/6)
__global__ __launch_bounds__(256)
void gat_phase2(const float* __restrict__ Whg, const float* __restrict__ wh1g,
                const float* __restrict__ wh2g,
                const unsigned long long* __restrict__ bits,
                float* __restrict__ out)
{
    __shared__ float swh2[512];
    __shared__ float swh1[32];
    __shared__ float whc[64 * 68];      // Wh chunk [64 j][64 o + pad]
    __shared__ float ptile[4 * 512];    // per-wave p [64 j][8 r]

    const int tid  = threadIdx.x;
    const int lane = tid & 63;
    const int wv   = tid >> 6;
    const int bx   = blockIdx.x;
    const int bt   = bx >> 4;
    const int i0   = (bx & 15) * 32;
    const size_t whbase = (size_t)bt * 32768;
    const unsigned long long lmask = 1ull << lane;

    swh2[tid]       = wh2g[bt * 512 + tid];
    swh2[tid + 256] = wh2g[bt * 512 + tid + 256];
    if (tid < 32) swh1[tid] = wh1g[bt * 512 + i0 + tid];
    __syncthreads();

    // ---- stats for this wave's 8 rows (lanes over j)
    float wh1r[8], mr[8], invr[8];
    #pragma unroll
    for (int r = 0; r < 8; ++r) {
        const int row = i0 + wv * 8 + r;
        const float wh1v = swh1[wv * 8 + r];
        wh1r[r] = wh1v;
        const unsigned long long* mrow = bits + (size_t)row * 8;
        float att[8];
        float mx = NEG_INF_V;
        #pragma unroll
        for (int k = 0; k < 8; ++k) {
            float e = wh1v + swh2[k * 64 + lane];
            e = (e > 0.f) ? e : LRELU_ALPHA * e;
            att[k] = (mrow[k] & lmask) ? e : NEG_INF_V;
            mx = fmaxf(mx, att[k]);
        }
        #pragma unroll
        for (int s = 32; s > 0; s >>= 1) mx = fmaxf(mx, __shfl_xor(mx, s));
        float sum = 0.f;
        #pragma unroll
        for (int k = 0; k < 8; ++k) sum += __expf(att[k] - mx);
        #pragma unroll
        for (int s = 32; s > 0; s >>= 1) sum += __shfl_xor(sum, s);
        mr[r] = mx;
        invr[r] = 1.f / sum;
    }

    float4 oacc[8];
    #pragma unroll
    for (int r = 0; r < 8; ++r) oacc[r] = make_float4(0.f, 0.f, 0.f, 0.f);

    float* pw = &ptile[wv * 512];
    const int o4 = (lane & 15) * 4;
    const int jq = lane >> 4;

    #pragma unroll 1
    for (int cc = 0; cc < 8; ++cc) {
        __syncthreads();                 // protect whc from previous FMA reads
        // ---- stage Wh chunk (coalesced float4)
        #pragma unroll
        for (int k = 0; k < 4; ++k) {
            int idx = k * 256 + tid;     // 0..1023 float4s
            int j   = idx >> 4;
            int o   = (idx & 15) * 4;
            *(float4*)&whc[j * 68 + o] =
                *(const float4*)&Whg[whbase + (size_t)cc * 4096 + idx * 4];
        }
        __syncthreads();

        // ---- p for this wave's rows (lane = local j), straight to ptile
        float wh2j = swh2[cc * 64 + lane];
        float pv[8];
        #pragma unroll
        for (int r = 0; r < 8; ++r) {
            const int row = i0 + wv * 8 + r;
            float e = wh1r[r] + wh2j;
            e = (e > 0.f) ? e : LRELU_ALPHA * e;
            float av = (bits[(size_t)row * 8 + cc] & lmask) ? e : NEG_INF_V;
            pv[r] = __expf(av - mr[r]) * invr[r];
        }
        *(float4*)&pw[lane * 8]     = make_float4(pv[0], pv[1], pv[2], pv[3]);
        *(float4*)&pw[lane * 8 + 4] = make_float4(pv[4], pv[5], pv[6], pv[7]);
        // same-wave DS ops are in-order: no barrier needed for ptile.

        // ---- FMA: lane=(o4,jq); 3 b128 LDS reads per 32 FMAs
        #pragma unroll 2
        for (int l = 0; l < 16; ++l) {
            int jl = l * 4 + jq;
            float4 whv = *(const float4*)&whc[jl * 68 + o4];
            float4 pa  = *(const float4*)&pw[jl * 8];
            float4 pb  = *(const float4*)&pw[jl * 8 + 4];
            FMA4(oacc[0], pa.x, whv);
            FMA4(oacc[1], pa.y, whv);
            FMA4(oacc[2], pa.z, whv);
            FMA4(oacc[3], pa.w, whv);
            FMA4(oacc[4], pb.x, whv);
            FMA4(oacc[5], pb.y, whv);
            FMA4(oacc[6], pb.z, whv);
            FMA4(oacc[7], pb.w, whv);
        }
    }

    // ---- reduce over jq groups, ELU, store
    const size_t obase = (size_t)bt * 32768;
    #pragma unroll
    for (int r = 0; r < 8; ++r) {
        float4 v = oacc[r];
        #pragma unroll
        for (int s = 16; s <= 32; s <<= 1) {
            v.x += __shfl_xor(v.x, s);
            v.y += __shfl_xor(v.y, s);
            v.z += __shfl_xor(v.z, s);
            v.w += __shfl_xor(v.w, s);
        }
        if (jq == 0) {
            float4 res;
            res.x = (v.x > 0.f) ? v.x : __expf(v.x) - 1.f;
            res.y = (v.y > 0.f) ? v.y : __expf(v.y) - 1.f;
            res.z = (v.z > 0.f) ? v.z : __expf(v.z) - 1.f;
            res.w = (v.w > 0.f) ? v.w : __expf(v.w) - 1.f;
            *(float4*)&out[obase + (size_t)(i0 + wv * 8 + r) * 64 + o4] = res;
        }
    }
}

extern "C" void kernel_launch(void* const* d_in, const int* in_sizes, int n_in,
                              void* d_out, int out_size, void* d_ws, size_t ws_size,
                              hipStream_t stream)
{
    const float* h   = (const float*)d_in[0];   // (16,12,512,64)
    const float* adj = (const float*)d_in[1];   // (512,512)
    const float* W   = (const float*)d_in[2];   // (64,64)
    const float* a   = (const float*)d_in[3];   // (128,1)
    float* out = (float*)d_out;                 // (16,12,512,64)

    // workspace layout (needs ~26 MB)
    unsigned long long* bits = (unsigned long long*)d_ws;            // 32 KB
    float* Whg  = (float*)((char*)d_ws + 32768);                     // 25.17 MB
    float* wh1g = Whg + (size_t)192 * 512 * 64;                      // 384 KB
    float* wh2g = wh1g + (size_t)192 * 512;                          // 384 KB

    adj_bits_kernel<<<512, 512, 0, stream>>>(adj, bits);
    gat_phase1<<<192, 256, 0, stream>>>(h, W, a, Whg, wh1g, wh2g);
    gat_phase2<<<3072, 256, 0, stream>>>(Whg, wh1g, wh2g, bits, out);
}

// Round 8
// 214.603 us; speedup vs baseline: 5.9710x; 1.2398x over previous
//
#include <hip/hip_runtime.h>

#define LRELU_ALPHA 0.2f
#define NEG_INF_V  -9.0e15f

// Round-8: (a) phase2 drops the stats pre-pass: softmax denom commutes with
// the matmul -> accumulate Sum exp(e-b)*Wh and Sum exp(e-b), divide at end.
// b_i = max(0, wh1_i + max_j wh2_j) is a valid stability bound (exp<=1) and
// ratios are exact for any b. max_j wh2 from a tiny per-bt kernel.
// (b) phase1 occupancy: 768 blocks (bt,quarter) x 2 chunks -> 12 waves/CU
// (was 4). Per-chunk code byte-identical to round 7 (proven correct).
// adj_bits unchanged; FMA loop unchanged.

#define FMA4(d, s, v)                          \
    d.x = fmaf(s, v.x, d.x);                   \
    d.y = fmaf(s, v.y, d.y);                   \
    d.z = fmaf(s, v.z, d.z);                   \
    d.w = fmaf(s, v.w, d.w);

__global__ __launch_bounds__(512)
void adj_bits_kernel(const float* __restrict__ adj, unsigned long long* __restrict__ bits)
{
    const int tid  = threadIdx.x;
    const int lane = tid & 63;
    const int w    = tid >> 6;
    const int g    = blockIdx.x * 8 + w;   // 0..4095
    const int row  = g >> 3;
    const int k    = g & 7;
    float v = adj[row * 512 + k * 64 + lane];
    unsigned long long m = __ballot(v > 0.f);
    if (lane == 0) bits[row * 8 + k] = m;
}

// ---------------- Phase 1: Wh = h@W, wh1, wh2 (to global ws) ----------------
// 768 blocks x 256 thr; block (bt, q) does chunks 2q, 2q+1 (64 nodes each).
// Per-chunk body byte-identical to round 7.
__global__ __launch_bounds__(256)
void gat_phase1(const float* __restrict__ h, const float* __restrict__ W,
                const float* __restrict__ a,
                float* __restrict__ Whg, float* __restrict__ wh1g,
                float* __restrict__ wh2g)
{
    __shared__ float sW[64 * 68];     // [k][o + pad]
    __shared__ float hT[64 * 68];     // [k][n_local + pad]

    const int tid  = threadIdx.x;
    const int lane = tid & 63;
    const int wv   = tid >> 6;        // 0..3
    const int bt   = blockIdx.x >> 2;
    const int q    = blockIdx.x & 3;
    const size_t base = (size_t)bt * 32768;

    const int o4 = (lane & 15) * 4;
    const int jq = lane >> 4;

    // stage W [k][o]: idx = k*64+o; lane-consecutive reads
    #pragma unroll
    for (int t = 0; t < 16; ++t) {
        int idx = t * 256 + tid;
        sW[(idx >> 6) * 68 + (idx & 63)] = W[idx];
    }
    const float4 a1v = *(const float4*)&a[o4];
    const float4 a2v = *(const float4*)&a[64 + o4];

    #pragma unroll 1
    for (int ci = 0; ci < 2; ++ci) {
        const int c  = q * 2 + ci;
        const int n0 = c * 64;
        __syncthreads();              // prev chunk's readers done (also covers sW staging)
        #pragma unroll
        for (int t = 0; t < 16; ++t) {
            hT[lane * 68 + t * 4 + wv] = h[base + (size_t)(n0 + t * 4 + wv) * 64 + lane];
        }
        __syncthreads();

        float4 acc[16];
        #pragma unroll
        for (int r = 0; r < 16; ++r) acc[r] = make_float4(0.f, 0.f, 0.f, 0.f);

        #pragma unroll 4
        for (int l = 0; l < 16; ++l) {
            int k = l * 4 + jq;
            float4 w4 = *(const float4*)&sW[k * 68 + o4];          // lane-varying
            const float* hrow = &hT[k * 68 + wv * 16];
            float4 ha = *(const float4*)&hrow[0];
            float4 hb = *(const float4*)&hrow[4];
            float4 hc = *(const float4*)&hrow[8];
            float4 hd = *(const float4*)&hrow[12];
            FMA4(acc[0],  ha.x, w4);
            FMA4(acc[1],  ha.y, w4);
            FMA4(acc[2],  ha.z, w4);
            FMA4(acc[3],  ha.w, w4);
            FMA4(acc[4],  hb.x, w4);
            FMA4(acc[5],  hb.y, w4);
            FMA4(acc[6],  hb.z, w4);
            FMA4(acc[7],  hb.w, w4);
            FMA4(acc[8],  hc.x, w4);
            FMA4(acc[9],  hc.y, w4);
            FMA4(acc[10], hc.z, w4);
            FMA4(acc[11], hc.w, w4);
            FMA4(acc[12], hd.x, w4);
            FMA4(acc[13], hd.y, w4);
            FMA4(acc[14], hd.z, w4);
            FMA4(acc[15], hd.w, w4);
        }

        // reduce over jq (lane bits 4,5); jq==0 lanes (0..15) hold Wh[n][o4..o4+3]
        #pragma unroll
        for (int r = 0; r < 16; ++r) {
            float4 v = acc[r];
            #pragma unroll
            for (int s = 16; s <= 32; s <<= 1) {
                v.x += __shfl_xor(v.x, s);
                v.y += __shfl_xor(v.y, s);
                v.z += __shfl_xor(v.z, s);
                v.w += __shfl_xor(v.w, s);
            }
            if (jq == 0) {
                const int n = n0 + wv * 16 + r;
                *(float4*)&Whg[base + (size_t)n * 64 + o4] = v;
                float t1 = v.x * a1v.x + v.y * a1v.y + v.z * a1v.z + v.w * a1v.w;
                float t2 = v.x * a2v.x + v.y * a2v.y + v.z * a2v.z + v.w * a2v.w;
                #pragma unroll
                for (int s = 1; s <= 8; s <<= 1) {   // lanes 0..15 all active
                    t1 += __shfl_xor(t1, s);
                    t2 += __shfl_xor(t2, s);
                }
                if (lane == 0) { wh1g[bt * 512 + n] = t1; wh2g[bt * 512 + n] = t2; }
            }
        }
    }
}

// ---------------- wh2 max per bt (for the softmax stability bound) ----------
__global__ __launch_bounds__(64)
void wh2_max_kernel(const float* __restrict__ wh2g, float* __restrict__ M2g)
{
    const int bt   = blockIdx.x;
    const int lane = threadIdx.x;
    float m = -3.4e38f;
    #pragma unroll
    for (int k = 0; k < 8; ++k) m = fmaxf(m, wh2g[bt * 512 + k * 64 + lane]);
    #pragma unroll
    for (int s = 32; s > 0; s >>= 1) m = fmaxf(m, __shfl_xor(m, s));
    if (lane == 0) M2g[bt] = m;
}

// ---------------- Phase 2: single-pass softmax-matmul + ELU ----------------
// out_row = (Sum_j exp(e-b) Wh_j) / (Sum_j exp(e-b)); b = max(0, wh1+M2).
__global__ __launch_bounds__(256)
void gat_phase2(const float* __restrict__ Whg, const float* __restrict__ wh1g,
                const float* __restrict__ wh2g, const float* __restrict__ M2g,
                const unsigned long long* __restrict__ bits,
                float* __restrict__ out)
{
    __shared__ float swh2[512];
    __shared__ float swh1[32];
    __shared__ float whc[64 * 68];      // Wh chunk [64 j][64 o + pad]
    __shared__ float ptile[4 * 512];    // per-wave p [64 j][8 r]

    const int tid  = threadIdx.x;
    const int lane = tid & 63;
    const int wv   = tid >> 6;
    const int bx   = blockIdx.x;
    const int bt   = bx >> 4;
    const int i0   = (bx & 15) * 32;
    const size_t whbase = (size_t)bt * 32768;
    const unsigned long long lmask = 1ull << lane;

    swh2[tid]       = wh2g[bt * 512 + tid];
    swh2[tid + 256] = wh2g[bt * 512 + tid + 256];
    if (tid < 32) swh1[tid] = wh1g[bt * 512 + i0 + tid];
    const float M2 = M2g[bt];
    __syncthreads();

    // per-row stability bound b = max(0, wh1 + M2)
    float wh1r[8], br[8], spart[8];
    #pragma unroll
    for (int r = 0; r < 8; ++r) {
        wh1r[r]  = swh1[wv * 8 + r];
        br[r]    = fmaxf(0.f, wh1r[r] + M2);
        spart[r] = 0.f;
    }

    float4 oacc[8];
    #pragma unroll
    for (int r = 0; r < 8; ++r) oacc[r] = make_float4(0.f, 0.f, 0.f, 0.f);

    float* pw = &ptile[wv * 512];
    const int o4 = (lane & 15) * 4;
    const int jq = lane >> 4;

    #pragma unroll 1
    for (int cc = 0; cc < 8; ++cc) {
        __syncthreads();                 // protect whc from previous FMA reads
        // ---- stage Wh chunk (coalesced float4)
        #pragma unroll
        for (int k = 0; k < 4; ++k) {
            int idx = k * 256 + tid;     // 0..1023 float4s
            int j   = idx >> 4;
            int o   = (idx & 15) * 4;
            *(float4*)&whc[j * 68 + o] =
                *(const float4*)&Whg[whbase + (size_t)cc * 4096 + idx * 4];
        }
        __syncthreads();

        // ---- unnormalized p for this wave's rows (lane = local j) -> ptile
        float wh2j = swh2[cc * 64 + lane];
        float pv[8];
        #pragma unroll
        for (int r = 0; r < 8; ++r) {
            const int row = i0 + wv * 8 + r;
            float e = wh1r[r] + wh2j;
            e = (e > 0.f) ? e : LRELU_ALPHA * e;
            float av = (bits[(size_t)row * 8 + cc] & lmask) ? e : NEG_INF_V;
            pv[r] = __expf(av - br[r]);   // masked: exp(-9e15) -> 0
            spart[r] += pv[r];
        }
        *(float4*)&pw[lane * 8]     = make_float4(pv[0], pv[1], pv[2], pv[3]);
        *(float4*)&pw[lane * 8 + 4] = make_float4(pv[4], pv[5], pv[6], pv[7]);
        // same-wave DS ops are in-order: no barrier needed for ptile.

        // ---- FMA: lane=(o4,jq); 3 b128 LDS reads per 32 FMAs
        #pragma unroll 2
        for (int l = 0; l < 16; ++l) {
            int jl = l * 4 + jq;
            float4 whv = *(const float4*)&whc[jl * 68 + o4];
            float4 pa  = *(const float4*)&pw[jl * 8];
            float4 pb  = *(const float4*)&pw[jl * 8 + 4];
            FMA4(oacc[0], pa.x, whv);
            FMA4(oacc[1], pa.y, whv);
            FMA4(oacc[2], pa.z, whv);
            FMA4(oacc[3], pa.w, whv);
            FMA4(oacc[4], pb.x, whv);
            FMA4(oacc[5], pb.y, whv);
            FMA4(oacc[6], pb.z, whv);
            FMA4(oacc[7], pb.w, whv);
        }
    }

    // ---- row sums (all 64 lanes), then jq-reduce, divide, ELU, store
    float ssum[8];
    #pragma unroll
    for (int r = 0; r < 8; ++r) {
        float s = spart[r];
        #pragma unroll
        for (int st = 32; st > 0; st >>= 1) s += __shfl_xor(s, st);
        ssum[r] = s;
    }

    const size_t obase = (size_t)bt * 32768;
    #pragma unroll
    for (int r = 0; r < 8; ++r) {
        float4 v = oacc[r];
        #pragma unroll
        for (int s = 16; s <= 32; s <<= 1) {
            v.x += __shfl_xor(v.x, s);
            v.y += __shfl_xor(v.y, s);
            v.z += __shfl_xor(v.z, s);
            v.w += __shfl_xor(v.w, s);
        }
        if (jq == 0) {
            const float isv = 1.f / ssum[r];
            v.x *= isv; v.y *= isv; v.z *= isv; v.w *= isv;
            float4 res;
            res.x = (v.x > 0.f) ? v.x : __expf(v.x) - 1.f;
            res.y = (v.y > 0.f) ? v.y : __expf(v.y) - 1.f;
            res.z = (v.z > 0.f) ? v.z : __expf(v.z) - 1.f;
            res.w = (v.w > 0.f) ? v.w : __expf(v.w) - 1.f;
            *(float4*)&out[obase + (size_t)(i0 + wv * 8 + r) * 64 + o4] = res;
        }
    }
}

extern "C" void kernel_launch(void* const* d_in, const int* in_sizes, int n_in,
                              void* d_out, int out_size, void* d_ws, size_t ws_size,
                              hipStream_t stream)
{
    const float* h   = (const float*)d_in[0];   // (16,12,512,64)
    const float* adj = (const float*)d_in[1];   // (512,512)
    const float* W   = (const float*)d_in[2];   // (64,64)
    const float* a   = (const float*)d_in[3];   // (128,1)
    float* out = (float*)d_out;                 // (16,12,512,64)

    // workspace layout (~26 MB)
    unsigned long long* bits = (unsigned long long*)d_ws;            // 32 KB
    float* Whg  = (float*)((char*)d_ws + 32768);                     // 25.17 MB
    float* wh1g = Whg + (size_t)192 * 512 * 64;                      // 384 KB
    float* wh2g = wh1g + (size_t)192 * 512;                          // 384 KB
    float* M2g  = wh2g + (size_t)192 * 512;                          // 768 B

    adj_bits_kernel<<<512, 512, 0, stream>>>(adj, bits);
    gat_phase1<<<768, 256, 0, stream>>>(h, W, a, Whg, wh1g, wh2g);
    wh2_max_kernel<<<192, 64, 0, stream>>>(wh2g, M2g);
    gat_phase2<<<3072, 256, 0, stream>>>(Whg, wh1g, wh2g, M2g, bits, out);
}